// Round 4
// baseline (1072.788 us; speedup 1.0000x reference)
//
#include <hip/hip_runtime.h>
#include <math.h>

#define BATCH 32
#define T 2048
#define D 1024
#define KW 31
#define CPAD 15
#define KEXT 62      // 2*31 conv-patch columns
#define KEXTP 64     // padded
#define KTOT 1088    // 1024 + 64
#define BM 128
#define BN 128
#define BK 32

typedef __bf16 bf16_8 __attribute__((ext_vector_type(8)));
typedef __bf16 bf16_4 __attribute__((ext_vector_type(4)));
typedef float  f32x4  __attribute__((ext_vector_type(4)));

__device__ __forceinline__ float tanh_fast(float x) {
    return 1.f - 2.f * __builtin_amdgcn_rcpf(__expf(2.f * x) + 1.f);
}

// ---------------- P1: Bext[d][kk] = bf16([Wm | Wloc]) ----------------
__global__ __launch_bounds__(256) void k_prep_b(const float* __restrict__ Wm,
                                                const float* __restrict__ Wloc,
                                                __bf16* __restrict__ Bext) {
    const int idx = blockIdx.x * 256 + threadIdx.x;
    const int d = idx / (KTOT / 4);
    const int kk = (idx % (KTOT / 4)) * 4;
    bf16_4 o;
    #pragma unroll
    for (int u = 0; u < 4; ++u) {
        const int k = kk + u;
        float val = 0.f;
        if (k < D) val = Wm[(size_t)d * D + k];
        else {
            const int j = k - D;
            if (j < KEXT) {
                const int c = (j >= KW) ? 1 : 0;
                const int kp = j - c * KW;
                val = Wloc[((size_t)d * 2 + c) * KW + kp];
            }
        }
        o[u] = (__bf16)val;
    }
    *(bf16_4*)(Bext + (size_t)d * KTOT + kk) = o;
}

// ---------------- P2: Aloc[b][t][j] = bf16 conv patches ----------------
__global__ __launch_bounds__(256) void k_prep_aloc(const float* __restrict__ prev,
                                                   const float* __restrict__ cum,
                                                   __bf16* __restrict__ Aloc) {
    const int idx = blockIdx.x * 256 + threadIdx.x;
    const int row = idx >> 4;          // b*T + t
    const int j0 = (idx & 15) * 4;
    const int b = row >> 11;
    const int t = row & (T - 1);
    bf16_4 o;
    #pragma unroll
    for (int u = 0; u < 4; ++u) {
        const int j = j0 + u;
        float val = 0.f;
        if (j < KEXT) {
            const int c = (j >= KW) ? 1 : 0;
            const int kp = j - c * KW;
            const int ts = t + kp - CPAD;
            if (ts >= 0 && ts < T)
                val = (c ? cum : prev)[(size_t)b * T + ts];
        }
        o[u] = (__bf16)val;
    }
    *(bf16_4*)(Aloc + (size_t)row * KEXTP + j0) = o;
}

// ---------------- K1: q = query @ Wq^T ----------------
__global__ __launch_bounds__(256) void k_q(const float* __restrict__ query,
                                           const float* __restrict__ Wq,
                                           float* __restrict__ qout) {
    int b = blockIdx.y;
    int w = threadIdx.x >> 6;
    int lane = threadIdx.x & 63;
    int d = blockIdx.x * 4 + w;
    const float* qrow = query + (size_t)b * D;
    const float* wrow = Wq + (size_t)d * D;
    float s = 0.f;
    #pragma unroll
    for (int i = 0; i < D / 64; ++i) s += qrow[lane + i * 64] * wrow[lane + i * 64];
    #pragma unroll
    for (int off = 32; off > 0; off >>= 1) s += __shfl_down(s, off, 64);
    if (lane == 0) qout[(size_t)b * D + d] = s;
}

// ---------------- K2: barrier-free MFMA GEMM, direct global->frag ----------------
// No LDS, no __syncthreads: A frags loaded as 2x f32x4 per row-chunk (cache-line
// perfect: 16 rows x 128B), cvt to bf16 in-reg; B frags as bf16_8 from L2-resident
// Bext. Twin waves share A rows / B cols via L1/L2. 4 blocks/CU target.
__global__ __launch_bounds__(256, 4) void k_gemm_e(
    const float* __restrict__ memory, const __bf16* __restrict__ Aloc,
    const __bf16* __restrict__ Bext, const float* __restrict__ qv,
    const float* __restrict__ vvec, float* __restrict__ e_part) {
    const int d0 = blockIdx.x * BN;   // d fastest: 8 x-blocks share A rows in LLC
    const int t0 = blockIdx.y * BM;
    const int b  = blockIdx.z;
    const int tid  = threadIdx.x;
    const int lane = tid & 63;
    const int w    = tid >> 6;
    const int wr   = w >> 1, wc = w & 1;
    const int q    = lane >> 4, m = lane & 15;

    f32x4 acc[4][4] = {};

    const float*  mb = memory + (size_t)b * T * D;
    int aoff[4], boff[4];
    #pragma unroll
    for (int i = 0; i < 4; ++i)
        aoff[i] = (t0 + wr * 64 + i * 16 + m) * D + q * 8;
    #pragma unroll
    for (int j = 0; j < 4; ++j)
        boff[j] = (d0 + wc * 64 + j * 16 + m) * KTOT + q * 8;

    #pragma unroll 2
    for (int k0 = 0; k0 < D; k0 += BK) {
        bf16_8 af[4], bfr[4];
        #pragma unroll
        for (int i = 0; i < 4; ++i) {
            const f32x4 x = *(const f32x4*)(mb + aoff[i] + k0);
            const f32x4 y = *(const f32x4*)(mb + aoff[i] + k0 + 4);
            #pragma unroll
            for (int u = 0; u < 4; ++u) {
                af[i][u]     = (__bf16)x[u];
                af[i][u + 4] = (__bf16)y[u];
            }
        }
        #pragma unroll
        for (int j = 0; j < 4; ++j)
            bfr[j] = *(const bf16_8*)(Bext + boff[j] + k0);
        #pragma unroll
        for (int i = 0; i < 4; ++i)
            #pragma unroll
            for (int j = 0; j < 4; ++j)
                acc[i][j] = __builtin_amdgcn_mfma_f32_16x16x32_bf16(af[i], bfr[j], acc[i][j], 0, 0, 0);
    }
    // conv-extension K-range (already bf16)
    const __bf16* lb = Aloc + (size_t)b * T * KEXTP;
    #pragma unroll
    for (int k0 = 0; k0 < KEXTP; k0 += BK) {
        bf16_8 af[4], bfr[4];
        #pragma unroll
        for (int i = 0; i < 4; ++i)
            af[i] = *(const bf16_8*)(lb + (t0 + wr * 64 + i * 16 + m) * KEXTP + q * 8 + k0);
        #pragma unroll
        for (int j = 0; j < 4; ++j)
            bfr[j] = *(const bf16_8*)(Bext + boff[j] + D + k0);
        #pragma unroll
        for (int i = 0; i < 4; ++i)
            #pragma unroll
            for (int j = 0; j < 4; ++j)
                acc[i][j] = __builtin_amdgcn_mfma_f32_16x16x32_bf16(af[i], bfr[j], acc[i][j], 0, 0, 0);
    }

    // epilogue: e(t) += sum_d tanh(acc + q[d]) * v[d]
    float qreg[4], vreg[4];
    #pragma unroll
    for (int j = 0; j < 4; ++j) {
        const int d = d0 + wc * 64 + j * 16 + m;
        qreg[j] = qv[(size_t)b * D + d];
        vreg[j] = vvec[d];
    }
    const int dch = blockIdx.x * 2 + wc;
    #pragma unroll
    for (int i = 0; i < 4; ++i) {
        #pragma unroll
        for (int r = 0; r < 4; ++r) {
            float s = 0.f;
            #pragma unroll
            for (int j = 0; j < 4; ++j)
                s += tanh_fast(acc[i][j][r] + qreg[j]) * vreg[j];
            #pragma unroll
            for (int off = 8; off > 0; off >>= 1)
                s += __shfl_down(s, off, 16);
            if (m == 0) {
                const int t = t0 + wr * 64 + i * 16 + q * 4 + r;
                e_part[((size_t)b * T + t) * 16 + dch] = s;
            }
        }
    }
}

// ---------------- K3: masked softmax over T (1024 threads/block) ----------------
__global__ __launch_bounds__(1024) void k_softmax(const float* __restrict__ e_part,
                                                  const int* __restrict__ mask,
                                                  float* __restrict__ aout) {
    const int b = blockIdx.x;
    const int tid = threadIdx.x;
    __shared__ float red[1024];
    float ev[2];
    float lmax = -INFINITY;
    #pragma unroll
    for (int i = 0; i < 2; ++i) {
        const int t = tid + i * 1024;
        const float* p = e_part + ((size_t)b * T + t) * 16;
        f32x4 s4 = {0.f, 0.f, 0.f, 0.f};
        #pragma unroll
        for (int c = 0; c < 4; ++c) s4 += *(const f32x4*)(p + c * 4);
        float s = s4[0] + s4[1] + s4[2] + s4[3];
        if (mask[(size_t)b * T + t] != 0) s = -INFINITY;
        ev[i] = s;
        lmax = fmaxf(lmax, s);
    }
    red[tid] = lmax; __syncthreads();
    for (int off = 512; off > 0; off >>= 1) {
        if (tid < off) red[tid] = fmaxf(red[tid], red[tid + off]);
        __syncthreads();
    }
    const float mx = red[0]; __syncthreads();
    float lsum = 0.f;
    #pragma unroll
    for (int i = 0; i < 2; ++i) {
        const float x = expf(ev[i] - mx);
        ev[i] = x;
        lsum += x;
    }
    red[tid] = lsum; __syncthreads();
    for (int off = 512; off > 0; off >>= 1) {
        if (tid < off) red[tid] += red[tid + off];
        __syncthreads();
    }
    const float inv = 1.f / red[0];
    #pragma unroll
    for (int i = 0; i < 2; ++i)
        aout[(size_t)b * T + tid + i * 1024] = ev[i] * inv;
}

// ---------------- K4: partial ctx, 64-t chunks (1024 blocks) ----------------
__global__ __launch_bounds__(256) void k_ctx_part(const float* __restrict__ memory,
                                                  const float* __restrict__ a,
                                                  float* __restrict__ ctx_part) {
    const int b = blockIdx.x;
    const int tc = blockIdx.y;       // 0..31
    const int d4 = threadIdx.x * 4;
    f32x4 acc = {0.f, 0.f, 0.f, 0.f};
    const float* mb = memory + ((size_t)b * T + (size_t)tc * 64) * D;
    const float* ab = a + (size_t)b * T + (size_t)tc * 64;
    #pragma unroll 4
    for (int t = 0; t < 64; ++t) {
        const float wgt = ab[t];
        const f32x4 m4 = *(const f32x4*)(mb + (size_t)t * D + d4);
        acc += wgt * m4;
    }
    *(f32x4*)(ctx_part + ((size_t)(b * 32 + tc)) * D + d4) = acc;
}

// ---------------- K5: reduce 32 ctx partials ----------------
__global__ __launch_bounds__(256) void k_ctx_red(const float* __restrict__ ctx_part,
                                                 float* __restrict__ ctx) {
    const int idx = blockIdx.x * 256 + threadIdx.x;
    const int b = idx >> 10, d = idx & 1023;
    float s = 0.f;
    #pragma unroll
    for (int tc = 0; tc < 32; ++tc) s += ctx_part[((size_t)(b * 32 + tc)) * D + d];
    ctx[idx] = s;
}

extern "C" void kernel_launch(void* const* d_in, const int* in_sizes, int n_in,
                              void* d_out, int out_size, void* d_ws, size_t ws_size,
                              hipStream_t stream) {
    const float* query  = (const float*)d_in[0];
    const float* memory = (const float*)d_in[1];
    const float* prev   = (const float*)d_in[2];
    const float* cum    = (const float*)d_in[3];
    const int*   mask   = (const int*)d_in[4];
    const float* Wq     = (const float*)d_in[5];
    const float* Wm     = (const float*)d_in[6];
    const float* Wloc   = (const float*)d_in[7];
    const float* v      = (const float*)d_in[8];

    float* out = (float*)d_out;
    float* ctx = out;               // [B, D]
    float* a   = out + BATCH * D;   // [B, T]

    char* ws = (char*)d_ws;
    float*  qv       = (float*)(ws + 0);                 // 128 KB
    float*  e_part   = (float*)(ws + 131072);            // 4 MB   [B,T,16]
    float*  ctx_part = (float*)(ws + 4325376);           // 4 MB   [B,32,D]
    __bf16* Bext     = (__bf16*)(ws + 8519680);          // 2.23 MB [1024,1088]
    __bf16* Aloc     = (__bf16*)(ws + 10747904);         // 8 MB   [B,T,64]

    k_prep_b<<<KTOT * D / (256 * 4), 256, 0, stream>>>(Wm, Wloc, Bext);
    k_prep_aloc<<<BATCH * T * 16 / 256, 256, 0, stream>>>(prev, cum, Aloc);
    k_q<<<dim3(D / 4, BATCH), 256, 0, stream>>>(query, Wq, qv);
    k_gemm_e<<<dim3(D / BN, T / BM, BATCH), 256, 0, stream>>>(memory, Aloc, Bext,
                                                              qv, v, e_part);
    k_softmax<<<BATCH, 1024, 0, stream>>>(e_part, mask, a);
    k_ctx_part<<<dim3(BATCH, 32), 256, 0, stream>>>(memory, a, ctx_part);
    k_ctx_red<<<(BATCH * D) / 256, 256, 0, stream>>>(ctx_part, ctx);
}